// Round 12
// baseline (553.615 us; speedup 1.0000x reference)
//
#include <hip/hip_runtime.h>

#define NN 100000
#define NE 600000
#define NG 64
#define FD 128
#define NB 98   // scan blocks of 1024: 98*1024 >= NN
#define EPAD 900000  // padded edge capacity: NE + 3*NN
#define NTILE16 6250   // 100000 / 16 row-tiles
#define GEMM_BLOCKS 512   // 2 blocks/CU (64 KB LDS each), 8 waves/block

typedef __attribute__((ext_vector_type(8))) short s8v;
typedef __attribute__((ext_vector_type(4))) float f4v;

__device__ inline float bflo(unsigned u) { return __uint_as_float(u << 16); }
__device__ inline float bfhi(unsigned u) { return __uint_as_float(u & 0xFFFF0000u); }
__device__ inline unsigned f2bfbits(float f) {  // round-to-nearest-even
  unsigned x = __float_as_uint(f);
  return (x + 0x7FFFu + ((x >> 16) & 1u)) >> 16;
}
__device__ inline unsigned pack2(float a, float b) { return f2bfbits(a) | (f2bfbits(b) << 16); }

// ---------------- weight cast: W f32 [K][N] -> WThi/WTlo bf16 [N][K], 3 weights in one ----------------
__global__ void k_castW3(const float* __restrict__ W1, const float* __restrict__ W2,
                         const float* __restrict__ W3, unsigned short* __restrict__ WTh,
                         unsigned short* __restrict__ WTl) {
  int e = blockIdx.x * 256 + threadIdx.x;   // grid covers 3*FD*FD
  int which = e / (FD * FD);
  int r = e - which * (FD * FD);
  if (which >= 3) return;
  const float* W = which == 0 ? W1 : (which == 1 ? W2 : W3);
  int k = r >> 7, n = r & 127;
  float v = W[r];
  unsigned hb = f2bfbits(v);
  float hf = __uint_as_float(hb << 16);
  unsigned lb = f2bfbits(v - hf);
  WTh[which * FD * FD + n * FD + k] = (unsigned short)hb;
  WTl[which * FD * FD + n * FD + k] = (unsigned short)lb;
}

// ---------------- degree / CSR build ----------------

__global__ void k_init(float* psum) {
  int i = blockIdx.x * 256 + threadIdx.x;
  if (i < NG * FD) psum[i] = 0.f;
}

__global__ void k_count(const int* __restrict__ col, int* __restrict__ counts) {
  int e = blockIdx.x * 256 + threadIdx.x;
  if (e < NE) atomicAdd(&counts[col[e]], 1);
}

__global__ void k_dinv(const int* __restrict__ counts, float* __restrict__ dinv) {
  int n = blockIdx.x * 256 + threadIdx.x;
  if (n < NN) dinv[n] = rsqrtf((float)counts[n] + 1.0f);
}

// 3-phase scan over PADDED counts: ceil(deg/4)*4 per node
__global__ void k_bsum(const int* __restrict__ counts, int* __restrict__ bsum) {
  __shared__ int wsm[16];
  int b = blockIdx.x, t = threadIdx.x;
  int i = b * 1024 + t;
  int x = (i < NN) ? ((counts[i] + 3) & ~3) : 0;
#pragma unroll
  for (int d = 32; d; d >>= 1) x += __shfl_down(x, d);
  if ((t & 63) == 0) wsm[t >> 6] = x;
  __syncthreads();
  if (t < 16) {
    int s = wsm[t];
#pragma unroll
    for (int d = 8; d; d >>= 1) s += __shfl_down(s, d);
    if (t == 0) bsum[b] = s;
  }
}

__global__ void k_bscan(const int* __restrict__ bsum, int* __restrict__ eb) {
  __shared__ int w0;
  int t = threadIdx.x;  // 128
  int x = (t < NB) ? bsum[t] : 0;
  int lane = t & 63;
  int inc = x;
#pragma unroll
  for (int d = 1; d < 64; d <<= 1) { int y = __shfl_up(inc, d); if (lane >= d) inc += y; }
  if (t == 63) w0 = inc;
  __syncthreads();
  int off = (t >= 64) ? w0 : 0;
  if (t < NB) eb[t] = off + inc - x;  // exclusive
}

__global__ void k_scan2(const int* __restrict__ counts, const int* __restrict__ eb,
                        int* __restrict__ indptr) {
  __shared__ int wsm[16];
  int b = blockIdx.x, t = threadIdx.x;
  int i = b * 1024 + t;
  int x = (i < NN) ? ((counts[i] + 3) & ~3) : 0;
  int lane = t & 63, wid = t >> 6;
  int inc = x;
#pragma unroll
  for (int d = 1; d < 64; d <<= 1) { int y = __shfl_up(inc, d); if (lane >= d) inc += y; }
  if (lane == 63) wsm[wid] = inc;
  __syncthreads();
  if (wid == 0) {
    int s = (lane < 16) ? wsm[lane] : 0;
#pragma unroll
    for (int d = 1; d < 16; d <<= 1) { int y = __shfl_up(s, d); if (lane >= d) s += y; }
    if (lane < 16) wsm[lane] = s;
  }
  __syncthreads();
  int woff = wid ? wsm[wid - 1] : 0;
  if (i < NN) indptr[i + 1] = eb[b] + woff + inc;
  if (i == 0) indptr[0] = 0;
}

// combined edge record: {src, nrm}; pad slots stay {0, 0.0f} from memset (exact no-ops)
__global__ void k_fill(const int* __restrict__ row, const int* __restrict__ col,
                       const int* __restrict__ indptr, int* __restrict__ cursor,
                       const float* __restrict__ dinv, uint2* __restrict__ edges) {
  int e = blockIdx.x * 256 + threadIdx.x;
  if (e >= NE) return;
  int c = col[e], r = row[e];
  int p = indptr[c] + atomicAdd(&cursor[c], 1);
  edges[p] = make_uint2((unsigned)r, __float_as_uint(dinv[r] * dinv[c]));
}

// batch is sorted: ranges by boundary detection
__global__ void k_ranges(const int* __restrict__ batch, int* __restrict__ starts,
                         int* __restrict__ ends) {
  int n = blockIdx.x * 256 + threadIdx.x;
  if (n >= NN) return;
  int g = batch[n];
  if (n == 0) {
    starts[g] = 0;
    for (int q = 0; q < g; ++q) { starts[q] = 0; ends[q] = 0; }
  } else {
    int gp = batch[n - 1];
    if (gp != g) {
      ends[gp] = n;
      starts[g] = n;
      for (int q = gp + 1; q < g; ++q) { starts[q] = n; ends[q] = n; }
    }
  }
  if (n == NN - 1) {
    ends[g] = NN;
    for (int q = g + 1; q < NG; ++q) { starts[q] = NN; ends[q] = NN; }
  }
}

// ---------------- MFMA GEMM: Hb[M,128] = A[M,128] @ (WThi+WTlo)^T ----------------
// W staged once in 64 KB LDS (XOR-swizzled, one barrier), then barrier-free
// persistent loop over 16-row tiles. Swapped MFMA operands (R11-verified): lane
// owns node r16 with 4 consecutive features per n-block. acc[8]=32 VGPR keeps
// total ~110 -> 4 waves/SIMD (16 waves/CU, fixes R9 starvation). All stores in
// ONE epilogue burst of 8x uint2 per lane (fixes R10/R11 write fragmentation:
// R9's burst measured WRITE=25.0 MB vs R11's in-loop 202 MB).
template <int F32A>
__global__ __launch_bounds__(512, 4) void k_gemm(const void* __restrict__ Aab,
                                                 const unsigned short* __restrict__ WThi,
                                                 const unsigned short* __restrict__ WTlo,
                                                 unsigned short* __restrict__ Hb) {
  __shared__ unsigned short wt[256 * 128];  // rows 0..127 = hi, 128..255 = lo
  int t = threadIdx.x, lane = t & 63, w = t >> 6;
  int r16 = lane & 15, kg = lane >> 4;

  {  // stage: thread t stages half a row (8 chunks of 8 us), swizzled ch = kap ^ (row&7)
    int rw = t >> 1, half = t & 1;
    const unsigned short* src = (rw < 128) ? (WThi + rw * FD) : (WTlo + (rw - 128) * FD);
#pragma unroll
    for (int j = 0; j < 8; ++j) {
      int kap = half * 8 + j;
      int ch = kap ^ (rw & 7);
      *(s8v*)&wt[rw * 128 + ch * 8] = *(const s8v*)(src + kap * 8);
    }
  }
  __syncthreads();

  for (int tile = blockIdx.x * 8 + w; tile < NTILE16; tile += GEMM_BLOCKS * 8) {
    int rowBase = tile * 16;

    // A fragments: lane holds A[row = rowBase + r16][k = c*32 + kg*8 + j]
    s8v afr[4];
    {
      int ar = rowBase + r16;
      if (F32A) {
        const float* ap = (const float*)Aab + (size_t)ar * FD + kg * 8;
#pragma unroll
        for (int c = 0; c < 4; ++c) {
          float4 p0 = *(const float4*)(ap + c * 32);
          float4 p1 = *(const float4*)(ap + c * 32 + 4);
          s8v f;
          f[0] = (short)f2bfbits(p0.x); f[1] = (short)f2bfbits(p0.y);
          f[2] = (short)f2bfbits(p0.z); f[3] = (short)f2bfbits(p0.w);
          f[4] = (short)f2bfbits(p1.x); f[5] = (short)f2bfbits(p1.y);
          f[6] = (short)f2bfbits(p1.z); f[7] = (short)f2bfbits(p1.w);
          afr[c] = f;
        }
      } else {
        const unsigned short* ap = (const unsigned short*)Aab + (size_t)ar * FD + kg * 8;
#pragma unroll
        for (int c = 0; c < 4; ++c) afr[c] = *(const s8v*)(ap + c * 32);
      }
    }

    f4v acc[8];
#pragma unroll
    for (int n = 0; n < 8; ++n) acc[n] = (f4v){0.f, 0.f, 0.f, 0.f};

#pragma unroll
    for (int n = 0; n < 8; ++n) {
      s8v bh[4], bl[4];
#pragma unroll
      for (int c = 0; c < 4; ++c) {
        int ch = (c * 4 + kg) ^ (r16 & 7);
        bh[c] = *(const s8v*)&wt[(n * 16 + r16) * 128 + ch * 8];
        bl[c] = *(const s8v*)&wt[(128 + n * 16 + r16) * 128 + ch * 8];
      }
      // swapped operands: W-fragment as A-operand -> D col = node, D row = feature
#pragma unroll
      for (int c = 0; c < 4; ++c)
        acc[n] = __builtin_amdgcn_mfma_f32_16x16x32_bf16(bh[c], afr[c], acc[n], 0, 0, 0);
#pragma unroll
      for (int c = 0; c < 4; ++c)
        acc[n] = __builtin_amdgcn_mfma_f32_16x16x32_bf16(bl[c], afr[c], acc[n], 0, 0, 0);
    }

    // epilogue burst: lane owns node rowBase+r16, features n*16 + kg*4 + {0..3}
    {
      int node = rowBase + r16;
      unsigned short* hp = Hb + (size_t)node * FD + kg * 4;
#pragma unroll
      for (int n = 0; n < 8; ++n) {
        uint2 v = make_uint2(pack2(acc[n][0], acc[n][1]), pack2(acc[n][2], acc[n][3]));
        *(uint2*)(hp + n * 16) = v;
      }
    }
  }
}

// ---------------- aggregation: 2 nodes per wave (32-lane halves), uint2 lanes ----------------
// CSR segments are padded to multiples of 4 -> single branch-free 4-unrolled loop.
__global__ __launch_bounds__(256) void k_agg(const uint2* __restrict__ H2,
                                             const int* __restrict__ indptr,
                                             const uint2* __restrict__ edges,
                                             const float* __restrict__ dinv,
                                             const float* __restrict__ bias,
                                             uint2* __restrict__ out2, int relu) {
  int wid = (blockIdx.x * 256 + threadIdx.x) >> 6;  // global wave id
  int hl = threadIdx.x & 31;                        // lane within half
  int n = wid * 2 + ((threadIdx.x >> 5) & 1);       // node of this half
  if (n >= NN) return;
  float dv = dinv[n];
  float s2 = dv * dv;
  uint2 u = H2[(size_t)n * 32 + hl];
  float a0 = s2 * bflo(u.x), a1 = s2 * bfhi(u.x);
  float a2 = s2 * bflo(u.y), a3 = s2 * bfhi(u.y);
  int e0 = indptr[n], e1 = indptr[n + 1];  // e1-e0 is a multiple of 4
  for (int e = e0; e < e1; e += 4) {
    uint2 q0 = edges[e], q1 = edges[e + 1], q2 = edges[e + 2], q3 = edges[e + 3];
    uint2 v0 = H2[(size_t)q0.x * 32 + hl];
    uint2 v1 = H2[(size_t)q1.x * 32 + hl];
    uint2 v2 = H2[(size_t)q2.x * 32 + hl];
    uint2 v3 = H2[(size_t)q3.x * 32 + hl];
    float w0 = __uint_as_float(q0.y), w1 = __uint_as_float(q1.y);
    float w2 = __uint_as_float(q2.y), w3 = __uint_as_float(q3.y);
    a0 += w0 * bflo(v0.x); a1 += w0 * bfhi(v0.x); a2 += w0 * bflo(v0.y); a3 += w0 * bfhi(v0.y);
    a0 += w1 * bflo(v1.x); a1 += w1 * bfhi(v1.x); a2 += w1 * bflo(v1.y); a3 += w1 * bfhi(v1.y);
    a0 += w2 * bflo(v2.x); a1 += w2 * bfhi(v2.x); a2 += w2 * bflo(v2.y); a3 += w2 * bfhi(v2.y);
    a0 += w3 * bflo(v3.x); a1 += w3 * bfhi(v3.x); a2 += w3 * bflo(v3.y); a3 += w3 * bfhi(v3.y);
  }
  a0 += bias[hl * 4];
  a1 += bias[hl * 4 + 1];
  a2 += bias[hl * 4 + 2];
  a3 += bias[hl * 4 + 3];
  if (relu) {
    a0 = fmaxf(a0, 0.f); a1 = fmaxf(a1, 0.f);
    a2 = fmaxf(a2, 0.f); a3 = fmaxf(a3, 0.f);
  }
  out2[(size_t)n * 32 + hl] = make_uint2(pack2(a0, a1), pack2(a2, a3));
}

// ---------------- mean pool: wave per 64-node chunk, lanes cover row as bf16x2 ----------------
#define PW 64  // nodes per wave
__global__ __launch_bounds__(256) void k_pool(const unsigned* __restrict__ H2,
                                              const int* __restrict__ batch,
                                              float* __restrict__ psum) {
  int wgl = (blockIdx.x * 256 + threadIdx.x) >> 6;  // global wave id
  int lane = threadIdx.x & 63;
  int n0 = wgl * PW;
  if (n0 >= NN) return;
  int n1 = n0 + PW; if (n1 > NN) n1 = NN;
  int g0 = batch[n0], g1 = batch[n1 - 1];
  float a0 = 0.f, a1 = 0.f;
  if (g0 == g1) {
    int n = n0;
    for (; n + 3 < n1; n += 4) {
      unsigned v0 = H2[(size_t)(n + 0) * 64 + lane];
      unsigned v1 = H2[(size_t)(n + 1) * 64 + lane];
      unsigned v2 = H2[(size_t)(n + 2) * 64 + lane];
      unsigned v3 = H2[(size_t)(n + 3) * 64 + lane];
      a0 += bflo(v0) + bflo(v1) + bflo(v2) + bflo(v3);
      a1 += bfhi(v0) + bfhi(v1) + bfhi(v2) + bfhi(v3);
    }
    for (; n < n1; ++n) {
      unsigned v = H2[(size_t)n * 64 + lane];
      a0 += bflo(v); a1 += bfhi(v);
    }
    atomicAdd(&psum[g0 * FD + lane * 2], a0);
    atomicAdd(&psum[g0 * FD + lane * 2 + 1], a1);
  } else {
    int g = g0;
    for (int n = n0; n < n1; ++n) {
      int gn = batch[n];
      if (gn != g) {
        atomicAdd(&psum[g * FD + lane * 2], a0);
        atomicAdd(&psum[g * FD + lane * 2 + 1], a1);
        a0 = 0.f; a1 = 0.f; g = gn;
      }
      unsigned v = H2[(size_t)n * 64 + lane];
      a0 += bflo(v); a1 += bfhi(v);
    }
    atomicAdd(&psum[g * FD + lane * 2], a0);
    atomicAdd(&psum[g * FD + lane * 2 + 1], a1);
  }
}

__global__ void k_head(const float* __restrict__ psum, const int* __restrict__ starts,
                       const int* __restrict__ ends, const float* __restrict__ Wl,
                       const float* __restrict__ bl, float* __restrict__ out) {
  int t = threadIdx.x;  // 128 = 64 graphs x 2 classes
  int g = t >> 1, c = t & 1;
  int cnt = ends[g] - starts[g];
  if (cnt < 0) cnt = 0;
  float inv = 1.f / (float)(cnt > 0 ? cnt : 1);
  float acc = 0.f;
  for (int k = 0; k < FD; ++k) acc += psum[g * FD + k] * Wl[k * 2 + c];
  out[g * 2 + c] = acc * inv + bl[c];
}

// ---------------- host ----------------

extern "C" void kernel_launch(void* const* d_in, const int* in_sizes, int n_in,
                              void* d_out, int out_size, void* d_ws, size_t ws_size,
                              hipStream_t stream) {
  const float* x  = (const float*)d_in[0];
  const int* ei   = (const int*)d_in[1];
  const int* bat  = (const int*)d_in[2];
  const float* W1 = (const float*)d_in[3];
  const float* b1 = (const float*)d_in[4];
  const float* W2 = (const float*)d_in[5];
  const float* b2 = (const float*)d_in[6];
  const float* W3 = (const float*)d_in[7];
  const float* b3 = (const float*)d_in[8];
  const float* Wl = (const float*)d_in[9];
  const float* bl = (const float*)d_in[10];
  float* out = (float*)d_out;

  char* ws = (char*)d_ws;
  size_t off = 0;
  auto alloc = [&](size_t bytes) {
    void* p = ws + off;
    off += (bytes + 255) & ~(size_t)255;
    return p;
  };
  int* counts  = (int*)alloc(NN * 4);
  int* cursor  = (int*)alloc(NN * 4);
  int* indptr  = (int*)alloc((NN + 1) * 4);
  float* dinv  = (float*)alloc(NN * 4);
  int* bsum    = (int*)alloc(NB * 4);
  int* eb      = (int*)alloc(NB * 4);
  int* starts  = (int*)alloc(NG * 4);
  int* ends    = (int*)alloc(NG * 4);
  float* psum  = (float*)alloc(NG * FD * 4);
  uint2* edges = (uint2*)alloc((size_t)EPAD * 8);
  unsigned short* Hb   = (unsigned short*)alloc((size_t)NN * FD * 2);
  unsigned short* Abuf = (unsigned short*)alloc((size_t)NN * FD * 2);
  unsigned short* WTh  = (unsigned short*)alloc(3 * FD * FD * 2);
  unsigned short* WTl  = (unsigned short*)alloc(3 * FD * FD * 2);

  const int* row = ei;
  const int* col = ei + NE;

  // counts + cursor are adjacent in ws: single memset covers both (and the pad gap)
  hipMemsetAsync(counts, 0, (size_t)((char*)cursor - (char*)counts) + NN * 4, stream);
  hipMemsetAsync(edges, 0, (size_t)EPAD * 8, stream);
  k_init<<<32, 256, 0, stream>>>(psum);
  k_castW3<<<(3 * FD * FD + 255) / 256, 256, 0, stream>>>(W1, W2, W3, WTh, WTl);
  k_ranges<<<(NN + 255) / 256, 256, 0, stream>>>(bat, starts, ends);
  k_count<<<(NE + 255) / 256, 256, 0, stream>>>(col, counts);
  k_dinv<<<(NN + 255) / 256, 256, 0, stream>>>(counts, dinv);
  k_bsum<<<NB, 1024, 0, stream>>>(counts, bsum);
  k_bscan<<<1, 128, 0, stream>>>(bsum, eb);
  k_scan2<<<NB, 1024, 0, stream>>>(counts, eb, indptr);
  k_fill<<<(NE + 255) / 256, 256, 0, stream>>>(row, col, indptr, cursor, dinv, edges);

  int aggGrid = (NN + 7) / 8;         // 8 nodes per block (2 per wave x 4 waves)
  int poolGrid = ((NN + PW - 1) / PW * 64 + 255) / 256;

  k_gemm<1><<<GEMM_BLOCKS, 512, 0, stream>>>(x, WTh, WTl, Hb);
  k_agg<<<aggGrid, 256, 0, stream>>>((const uint2*)Hb, indptr, edges, dinv, b1,
                                     (uint2*)Abuf, 1);
  k_gemm<0><<<GEMM_BLOCKS, 512, 0, stream>>>(Abuf, WTh + FD * FD, WTl + FD * FD, Hb);
  k_agg<<<aggGrid, 256, 0, stream>>>((const uint2*)Hb, indptr, edges, dinv, b2,
                                     (uint2*)Abuf, 1);
  k_gemm<0><<<GEMM_BLOCKS, 512, 0, stream>>>(Abuf, WTh + 2 * FD * FD, WTl + 2 * FD * FD, Hb);
  k_agg<<<aggGrid, 256, 0, stream>>>((const uint2*)Hb, indptr, edges, dinv, b3,
                                     (uint2*)Abuf, 0);

  k_pool<<<poolGrid, 256, 0, stream>>>((const unsigned*)Abuf, bat, psum);
  k_head<<<1, 128, 0, stream>>>(psum, starts, ends, Wl, bl, out);
}

// Round 13
// 273.078 us; speedup vs baseline: 2.0273x; 2.0273x over previous
//
#include <hip/hip_runtime.h>

#define NN 100000
#define NE 600000
#define NG 64
#define FD 128
#define NB 98   // scan blocks of 1024: 98*1024 >= NN
#define EPAD 900000  // padded edge capacity: NE + 3*NN
#define NTILE16 6250   // 100000 / 16 row-tiles
#define GEMM_BLOCKS 512   // 2 blocks/CU (64 KB LDS each), 4 waves/block

typedef __attribute__((ext_vector_type(8))) short s8v;
typedef __attribute__((ext_vector_type(4))) float f4v;

__device__ inline float bflo(unsigned u) { return __uint_as_float(u << 16); }
__device__ inline float bfhi(unsigned u) { return __uint_as_float(u & 0xFFFF0000u); }
__device__ inline unsigned f2bfbits(float f) {  // round-to-nearest-even
  unsigned x = __float_as_uint(f);
  return (x + 0x7FFFu + ((x >> 16) & 1u)) >> 16;
}
__device__ inline unsigned pack2(float a, float b) { return f2bfbits(a) | (f2bfbits(b) << 16); }

// ---------------- weight cast: W f32 [K][N] -> WThi/WTlo bf16 [N][K], 3 weights in one ----------------
__global__ void k_castW3(const float* __restrict__ W1, const float* __restrict__ W2,
                         const float* __restrict__ W3, unsigned short* __restrict__ WTh,
                         unsigned short* __restrict__ WTl) {
  int e = blockIdx.x * 256 + threadIdx.x;   // grid covers 3*FD*FD
  int which = e / (FD * FD);
  int r = e - which * (FD * FD);
  if (which >= 3) return;
  const float* W = which == 0 ? W1 : (which == 1 ? W2 : W3);
  int k = r >> 7, n = r & 127;
  float v = W[r];
  unsigned hb = f2bfbits(v);
  float hf = __uint_as_float(hb << 16);
  unsigned lb = f2bfbits(v - hf);
  WTh[which * FD * FD + n * FD + k] = (unsigned short)hb;
  WTl[which * FD * FD + n * FD + k] = (unsigned short)lb;
}

// ---------------- degree / CSR build ----------------

__global__ void k_init(float* psum) {
  int i = blockIdx.x * 256 + threadIdx.x;
  if (i < NG * FD) psum[i] = 0.f;
}

__global__ void k_count(const int* __restrict__ col, int* __restrict__ counts) {
  int e = blockIdx.x * 256 + threadIdx.x;
  if (e < NE) atomicAdd(&counts[col[e]], 1);
}

__global__ void k_dinv(const int* __restrict__ counts, float* __restrict__ dinv) {
  int n = blockIdx.x * 256 + threadIdx.x;
  if (n < NN) dinv[n] = rsqrtf((float)counts[n] + 1.0f);
}

// 3-phase scan over PADDED counts: ceil(deg/4)*4 per node
__global__ void k_bsum(const int* __restrict__ counts, int* __restrict__ bsum) {
  __shared__ int wsm[16];
  int b = blockIdx.x, t = threadIdx.x;
  int i = b * 1024 + t;
  int x = (i < NN) ? ((counts[i] + 3) & ~3) : 0;
#pragma unroll
  for (int d = 32; d; d >>= 1) x += __shfl_down(x, d);
  if ((t & 63) == 0) wsm[t >> 6] = x;
  __syncthreads();
  if (t < 16) {
    int s = wsm[t];
#pragma unroll
    for (int d = 8; d; d >>= 1) s += __shfl_down(s, d);
    if (t == 0) bsum[b] = s;
  }
}

__global__ void k_bscan(const int* __restrict__ bsum, int* __restrict__ eb) {
  __shared__ int w0;
  int t = threadIdx.x;  // 128
  int x = (t < NB) ? bsum[t] : 0;
  int lane = t & 63;
  int inc = x;
#pragma unroll
  for (int d = 1; d < 64; d <<= 1) { int y = __shfl_up(inc, d); if (lane >= d) inc += y; }
  if (t == 63) w0 = inc;
  __syncthreads();
  int off = (t >= 64) ? w0 : 0;
  if (t < NB) eb[t] = off + inc - x;  // exclusive
}

__global__ void k_scan2(const int* __restrict__ counts, const int* __restrict__ eb,
                        int* __restrict__ indptr) {
  __shared__ int wsm[16];
  int b = blockIdx.x, t = threadIdx.x;
  int i = b * 1024 + t;
  int x = (i < NN) ? ((counts[i] + 3) & ~3) : 0;
  int lane = t & 63, wid = t >> 6;
  int inc = x;
#pragma unroll
  for (int d = 1; d < 64; d <<= 1) { int y = __shfl_up(inc, d); if (lane >= d) inc += y; }
  if (lane == 63) wsm[wid] = inc;
  __syncthreads();
  if (wid == 0) {
    int s = (lane < 16) ? wsm[lane] : 0;
#pragma unroll
    for (int d = 1; d < 16; d <<= 1) { int y = __shfl_up(s, d); if (lane >= d) s += y; }
    if (lane < 16) wsm[lane] = s;
  }
  __syncthreads();
  int woff = wid ? wsm[wid - 1] : 0;
  if (i < NN) indptr[i + 1] = eb[b] + woff + inc;
  if (i == 0) indptr[0] = 0;
}

// combined edge record: {src, nrm}; pad slots stay {0, 0.0f} from memset (exact no-ops)
__global__ void k_fill(const int* __restrict__ row, const int* __restrict__ col,
                       const int* __restrict__ indptr, int* __restrict__ cursor,
                       const float* __restrict__ dinv, uint2* __restrict__ edges) {
  int e = blockIdx.x * 256 + threadIdx.x;
  if (e >= NE) return;
  int c = col[e], r = row[e];
  int p = indptr[c] + atomicAdd(&cursor[c], 1);
  edges[p] = make_uint2((unsigned)r, __float_as_uint(dinv[r] * dinv[c]));
}

// batch is sorted: ranges by boundary detection
__global__ void k_ranges(const int* __restrict__ batch, int* __restrict__ starts,
                         int* __restrict__ ends) {
  int n = blockIdx.x * 256 + threadIdx.x;
  if (n >= NN) return;
  int g = batch[n];
  if (n == 0) {
    starts[g] = 0;
    for (int q = 0; q < g; ++q) { starts[q] = 0; ends[q] = 0; }
  } else {
    int gp = batch[n - 1];
    if (gp != g) {
      ends[gp] = n;
      starts[g] = n;
      for (int q = gp + 1; q < g; ++q) { starts[q] = n; ends[q] = n; }
    }
  }
  if (n == NN - 1) {
    ends[g] = NN;
    for (int q = g + 1; q < NG; ++q) { starts[q] = NN; ends[q] = NN; }
  }
}

// ---------------- MFMA GEMM: Hb[M,128] = A[M,128] @ (WThi+WTlo)^T ----------------
// 256-thread blocks, plain __launch_bounds__(256) — NO min-wave cap. R10-R12's
// (512,4) pinned VGPR to 64 and spilled acc to scratch (symmetric 100-217 MB
// HBM read+write amplification); R9's uncapped build (VGPR=200) wrote exactly
// 25.0 MB. W staged once in 64 KB LDS (XOR-swizzled, one barrier), barrier-free
// persistent loop over 16-row tiles, swapped MFMA operands, uint2 burst epilogue.
// A-loads for tile t+1 are issued BEFORE tile t's compute (raw, converted at
// use): each load gets ~800 cyc of MFMA/LDS work to complete -> HBM latency
// hidden even at 8 waves/CU.
template <int F32A>
__global__ __launch_bounds__(256) void k_gemm(const void* __restrict__ Aab,
                                              const unsigned short* __restrict__ WThi,
                                              const unsigned short* __restrict__ WTlo,
                                              unsigned short* __restrict__ Hb) {
  __shared__ unsigned short wt[256 * 128];  // rows 0..127 = hi, 128..255 = lo
  int t = threadIdx.x, lane = t & 63, w = t >> 6;
  int r16 = lane & 15, kg = lane >> 4;

  {  // stage: thread t stages row t (16 chunks of 8 us), swizzled ch = j ^ (row&7)
    const unsigned short* src = (t < 128) ? (WThi + t * FD) : (WTlo + (t - 128) * FD);
#pragma unroll
    for (int j = 0; j < 16; ++j) {
      int ch = j ^ (t & 7);
      *(s8v*)&wt[t * 128 + ch * 8] = *(const s8v*)(src + j * 8);
    }
  }
  __syncthreads();

  const int stride = GEMM_BLOCKS * 4;
  int tile = blockIdx.x * 4 + w;   // 2048 waves over 6250 tiles (~3 each)

  // raw A prefetch registers (current / next)
  float4 curF[8], nxtF[8];
  s8v curB[4], nxtB[4];

  {  // load current tile's A (raw)
    int ar = tile * 16 + r16;
    if (F32A) {
      const float* ap = (const float*)Aab + (size_t)ar * FD + kg * 8;
#pragma unroll
      for (int c = 0; c < 4; ++c) {
        curF[c * 2] = *(const float4*)(ap + c * 32);
        curF[c * 2 + 1] = *(const float4*)(ap + c * 32 + 4);
      }
    } else {
      const unsigned short* ap = (const unsigned short*)Aab + (size_t)ar * FD + kg * 8;
#pragma unroll
      for (int c = 0; c < 4; ++c) curB[c] = *(const s8v*)(ap + c * 32);
    }
  }

  while (tile < NTILE16) {
    int next = tile + stride;
    int nld = (next < NTILE16) ? next : tile;  // dummy reload on last iter

    {  // issue next tile's A loads now — they complete under this tile's compute
      int ar = nld * 16 + r16;
      if (F32A) {
        const float* ap = (const float*)Aab + (size_t)ar * FD + kg * 8;
#pragma unroll
        for (int c = 0; c < 4; ++c) {
          nxtF[c * 2] = *(const float4*)(ap + c * 32);
          nxtF[c * 2 + 1] = *(const float4*)(ap + c * 32 + 4);
        }
      } else {
        const unsigned short* ap = (const unsigned short*)Aab + (size_t)ar * FD + kg * 8;
#pragma unroll
        for (int c = 0; c < 4; ++c) nxtB[c] = *(const s8v*)(ap + c * 32);
      }
    }

    // convert current raw A -> bf16 fragments
    s8v afr[4];
    if (F32A) {
#pragma unroll
      for (int c = 0; c < 4; ++c) {
        float4 p0 = curF[c * 2], p1 = curF[c * 2 + 1];
        s8v f;
        f[0] = (short)f2bfbits(p0.x); f[1] = (short)f2bfbits(p0.y);
        f[2] = (short)f2bfbits(p0.z); f[3] = (short)f2bfbits(p0.w);
        f[4] = (short)f2bfbits(p1.x); f[5] = (short)f2bfbits(p1.y);
        f[6] = (short)f2bfbits(p1.z); f[7] = (short)f2bfbits(p1.w);
        afr[c] = f;
      }
    } else {
#pragma unroll
      for (int c = 0; c < 4; ++c) afr[c] = curB[c];
    }

    f4v acc[8];
#pragma unroll
    for (int n = 0; n < 8; ++n) acc[n] = (f4v){0.f, 0.f, 0.f, 0.f};

#pragma unroll
    for (int n = 0; n < 8; ++n) {
      s8v bh[4], bl[4];
#pragma unroll
      for (int c = 0; c < 4; ++c) {
        int ch = (c * 4 + kg) ^ (r16 & 7);
        bh[c] = *(const s8v*)&wt[(n * 16 + r16) * 128 + ch * 8];
        bl[c] = *(const s8v*)&wt[(128 + n * 16 + r16) * 128 + ch * 8];
      }
      // swapped operands: W-fragment as A-operand -> D col = node, D row = feature
#pragma unroll
      for (int c = 0; c < 4; ++c)
        acc[n] = __builtin_amdgcn_mfma_f32_16x16x32_bf16(bh[c], afr[c], acc[n], 0, 0, 0);
#pragma unroll
      for (int c = 0; c < 4; ++c)
        acc[n] = __builtin_amdgcn_mfma_f32_16x16x32_bf16(bl[c], afr[c], acc[n], 0, 0, 0);
    }

    // epilogue burst: lane owns node tile*16+r16, features n*16 + kg*4 + {0..3}
    {
      int node = tile * 16 + r16;
      unsigned short* hp = Hb + (size_t)node * FD + kg * 4;
#pragma unroll
      for (int n = 0; n < 8; ++n) {
        uint2 v = make_uint2(pack2(acc[n][0], acc[n][1]), pack2(acc[n][2], acc[n][3]));
        *(uint2*)(hp + n * 16) = v;
      }
    }

    // rotate prefetch
    if (F32A) {
#pragma unroll
      for (int c = 0; c < 8; ++c) curF[c] = nxtF[c];
    } else {
#pragma unroll
      for (int c = 0; c < 4; ++c) curB[c] = nxtB[c];
    }
    tile = next;
  }
}

// ---------------- aggregation: 2 nodes per wave (32-lane halves), uint2 lanes ----------------
// CSR segments are padded to multiples of 4 -> single branch-free 4-unrolled loop.
__global__ __launch_bounds__(256) void k_agg(const uint2* __restrict__ H2,
                                             const int* __restrict__ indptr,
                                             const uint2* __restrict__ edges,
                                             const float* __restrict__ dinv,
                                             const float* __restrict__ bias,
                                             uint2* __restrict__ out2, int relu) {
  int wid = (blockIdx.x * 256 + threadIdx.x) >> 6;  // global wave id
  int hl = threadIdx.x & 31;                        // lane within half
  int n = wid * 2 + ((threadIdx.x >> 5) & 1);       // node of this half
  if (n >= NN) return;
  float dv = dinv[n];
  float s2 = dv * dv;
  uint2 u = H2[(size_t)n * 32 + hl];
  float a0 = s2 * bflo(u.x), a1 = s2 * bfhi(u.x);
  float a2 = s2 * bflo(u.y), a3 = s2 * bfhi(u.y);
  int e0 = indptr[n], e1 = indptr[n + 1];  // e1-e0 is a multiple of 4
  for (int e = e0; e < e1; e += 4) {
    uint2 q0 = edges[e], q1 = edges[e + 1], q2 = edges[e + 2], q3 = edges[e + 3];
    uint2 v0 = H2[(size_t)q0.x * 32 + hl];
    uint2 v1 = H2[(size_t)q1.x * 32 + hl];
    uint2 v2 = H2[(size_t)q2.x * 32 + hl];
    uint2 v3 = H2[(size_t)q3.x * 32 + hl];
    float w0 = __uint_as_float(q0.y), w1 = __uint_as_float(q1.y);
    float w2 = __uint_as_float(q2.y), w3 = __uint_as_float(q3.y);
    a0 += w0 * bflo(v0.x); a1 += w0 * bfhi(v0.x); a2 += w0 * bflo(v0.y); a3 += w0 * bfhi(v0.y);
    a0 += w1 * bflo(v1.x); a1 += w1 * bfhi(v1.x); a2 += w1 * bflo(v1.y); a3 += w1 * bfhi(v1.y);
    a0 += w2 * bflo(v2.x); a1 += w2 * bfhi(v2.x); a2 += w2 * bflo(v2.y); a3 += w2 * bfhi(v2.y);
    a0 += w3 * bflo(v3.x); a1 += w3 * bfhi(v3.x); a2 += w3 * bflo(v3.y); a3 += w3 * bfhi(v3.y);
  }
  a0 += bias[hl * 4];
  a1 += bias[hl * 4 + 1];
  a2 += bias[hl * 4 + 2];
  a3 += bias[hl * 4 + 3];
  if (relu) {
    a0 = fmaxf(a0, 0.f); a1 = fmaxf(a1, 0.f);
    a2 = fmaxf(a2, 0.f); a3 = fmaxf(a3, 0.f);
  }
  out2[(size_t)n * 32 + hl] = make_uint2(pack2(a0, a1), pack2(a2, a3));
}

// ---------------- mean pool: wave per 64-node chunk, lanes cover row as bf16x2 ----------------
#define PW 64  // nodes per wave
__global__ __launch_bounds__(256) void k_pool(const unsigned* __restrict__ H2,
                                              const int* __restrict__ batch,
                                              float* __restrict__ psum) {
  int wgl = (blockIdx.x * 256 + threadIdx.x) >> 6;  // global wave id
  int lane = threadIdx.x & 63;
  int n0 = wgl * PW;
  if (n0 >= NN) return;
  int n1 = n0 + PW; if (n1 > NN) n1 = NN;
  int g0 = batch[n0], g1 = batch[n1 - 1];
  float a0 = 0.f, a1 = 0.f;
  if (g0 == g1) {
    int n = n0;
    for (; n + 3 < n1; n += 4) {
      unsigned v0 = H2[(size_t)(n + 0) * 64 + lane];
      unsigned v1 = H2[(size_t)(n + 1) * 64 + lane];
      unsigned v2 = H2[(size_t)(n + 2) * 64 + lane];
      unsigned v3 = H2[(size_t)(n + 3) * 64 + lane];
      a0 += bflo(v0) + bflo(v1) + bflo(v2) + bflo(v3);
      a1 += bfhi(v0) + bfhi(v1) + bfhi(v2) + bfhi(v3);
    }
    for (; n < n1; ++n) {
      unsigned v = H2[(size_t)n * 64 + lane];
      a0 += bflo(v); a1 += bfhi(v);
    }
    atomicAdd(&psum[g0 * FD + lane * 2], a0);
    atomicAdd(&psum[g0 * FD + lane * 2 + 1], a1);
  } else {
    int g = g0;
    for (int n = n0; n < n1; ++n) {
      int gn = batch[n];
      if (gn != g) {
        atomicAdd(&psum[g * FD + lane * 2], a0);
        atomicAdd(&psum[g * FD + lane * 2 + 1], a1);
        a0 = 0.f; a1 = 0.f; g = gn;
      }
      unsigned v = H2[(size_t)n * 64 + lane];
      a0 += bflo(v); a1 += bfhi(v);
    }
    atomicAdd(&psum[g * FD + lane * 2], a0);
    atomicAdd(&psum[g * FD + lane * 2 + 1], a1);
  }
}

__global__ void k_head(const float* __restrict__ psum, const int* __restrict__ starts,
                       const int* __restrict__ ends, const float* __restrict__ Wl,
                       const float* __restrict__ bl, float* __restrict__ out) {
  int t = threadIdx.x;  // 128 = 64 graphs x 2 classes
  int g = t >> 1, c = t & 1;
  int cnt = ends[g] - starts[g];
  if (cnt < 0) cnt = 0;
  float inv = 1.f / (float)(cnt > 0 ? cnt : 1);
  float acc = 0.f;
  for (int k = 0; k < FD; ++k) acc += psum[g * FD + k] * Wl[k * 2 + c];
  out[g * 2 + c] = acc * inv + bl[c];
}

// ---------------- host ----------------

extern "C" void kernel_launch(void* const* d_in, const int* in_sizes, int n_in,
                              void* d_out, int out_size, void* d_ws, size_t ws_size,
                              hipStream_t stream) {
  const float* x  = (const float*)d_in[0];
  const int* ei   = (const int*)d_in[1];
  const int* bat  = (const int*)d_in[2];
  const float* W1 = (const float*)d_in[3];
  const float* b1 = (const float*)d_in[4];
  const float* W2 = (const float*)d_in[5];
  const float* b2 = (const float*)d_in[6];
  const float* W3 = (const float*)d_in[7];
  const float* b3 = (const float*)d_in[8];
  const float* Wl = (const float*)d_in[9];
  const float* bl = (const float*)d_in[10];
  float* out = (float*)d_out;

  char* ws = (char*)d_ws;
  size_t off = 0;
  auto alloc = [&](size_t bytes) {
    void* p = ws + off;
    off += (bytes + 255) & ~(size_t)255;
    return p;
  };
  int* counts  = (int*)alloc(NN * 4);
  int* cursor  = (int*)alloc(NN * 4);
  int* indptr  = (int*)alloc((NN + 1) * 4);
  float* dinv  = (float*)alloc(NN * 4);
  int* bsum    = (int*)alloc(NB * 4);
  int* eb      = (int*)alloc(NB * 4);
  int* starts  = (int*)alloc(NG * 4);
  int* ends    = (int*)alloc(NG * 4);
  float* psum  = (float*)alloc(NG * FD * 4);
  uint2* edges = (uint2*)alloc((size_t)EPAD * 8);
  unsigned short* Hb   = (unsigned short*)alloc((size_t)NN * FD * 2);
  unsigned short* Abuf = (unsigned short*)alloc((size_t)NN * FD * 2);
  unsigned short* WTh  = (unsigned short*)alloc(3 * FD * FD * 2);
  unsigned short* WTl  = (unsigned short*)alloc(3 * FD * FD * 2);

  const int* row = ei;
  const int* col = ei + NE;

  // counts + cursor are adjacent in ws: single memset covers both (and the pad gap)
  hipMemsetAsync(counts, 0, (size_t)((char*)cursor - (char*)counts) + NN * 4, stream);
  hipMemsetAsync(edges, 0, (size_t)EPAD * 8, stream);
  k_init<<<32, 256, 0, stream>>>(psum);
  k_castW3<<<(3 * FD * FD + 255) / 256, 256, 0, stream>>>(W1, W2, W3, WTh, WTl);
  k_ranges<<<(NN + 255) / 256, 256, 0, stream>>>(bat, starts, ends);
  k_count<<<(NE + 255) / 256, 256, 0, stream>>>(col, counts);
  k_dinv<<<(NN + 255) / 256, 256, 0, stream>>>(counts, dinv);
  k_bsum<<<NB, 1024, 0, stream>>>(counts, bsum);
  k_bscan<<<1, 128, 0, stream>>>(bsum, eb);
  k_scan2<<<NB, 1024, 0, stream>>>(counts, eb, indptr);
  k_fill<<<(NE + 255) / 256, 256, 0, stream>>>(row, col, indptr, cursor, dinv, edges);

  int aggGrid = (NN + 7) / 8;         // 8 nodes per block (2 per wave x 4 waves)
  int poolGrid = ((NN + PW - 1) / PW * 64 + 255) / 256;

  k_gemm<1><<<GEMM_BLOCKS, 256, 0, stream>>>(x, WTh, WTl, Hb);
  k_agg<<<aggGrid, 256, 0, stream>>>((const uint2*)Hb, indptr, edges, dinv, b1,
                                     (uint2*)Abuf, 1);
  k_gemm<0><<<GEMM_BLOCKS, 256, 0, stream>>>(Abuf, WTh + FD * FD, WTl + FD * FD, Hb);
  k_agg<<<aggGrid, 256, 0, stream>>>((const uint2*)Hb, indptr, edges, dinv, b2,
                                     (uint2*)Abuf, 1);
  k_gemm<0><<<GEMM_BLOCKS, 256, 0, stream>>>(Abuf, WTh + 2 * FD * FD, WTl + 2 * FD * FD, Hb);
  k_agg<<<aggGrid, 256, 0, stream>>>((const uint2*)Hb, indptr, edges, dinv, b3,
                                     (uint2*)Abuf, 0);

  k_pool<<<poolGrid, 256, 0, stream>>>((const unsigned*)Abuf, bat, psum);
  k_head<<<1, 128, 0, stream>>>(psum, starts, ends, Wl, bl, out);
}